// Round 10
// baseline (802.712 us; speedup 1.0000x reference)
//
#include <hip/hip_runtime.h>
#include <cstdint>
#include <cstddef>

// Problem constants
#define RN 12800   // routes
#define CN 25      // caps
#define ON 64      // out channels
#define IN_ 8      // in channels
#define BN 8       // batch
#define SOUT (BN*CN*ON)   // 12800 output elems

#define RPC 64            // routes per chunk
#define NRC (RN / RPC)    // 200 chunks
#define NFIN (BN * CN)    // 200 finalize blocks

typedef float    f4x __attribute__((ext_vector_type(4)));
typedef uint32_t u4x __attribute__((ext_vector_type(4)));

// ---- bf16 helpers (RNE) ----
__device__ __forceinline__ uint32_t pack_bf16(float a, float b) {
    uint32_t ua = __float_as_uint(a);
    uint32_t ub = __float_as_uint(b);
    ua = (ua + 0x7fffu + ((ua >> 16) & 1u)) >> 16;          // bf16(a) low half
    ub = (ub + 0x7fffu + ((ub >> 16) & 1u)) & 0xffff0000u;  // bf16(b) high half
    return ua | ub;
}
__device__ __forceinline__ float lo_bf16(uint32_t q) { return __uint_as_float(q << 16); }
__device__ __forceinline__ float hi_bf16(uint32_t q) { return __uint_as_float(q & 0xffff0000u); }
__device__ __forceinline__ float squashf(float s) { return s * fabsf(s) / (1.f + s * s); }

// ============================================================================
// pass0 (R8-identical): u = W·x; U stored bf16 nt [r][c][o]; W loads nt.
// Sp[chunk] partials regular. block = 320 thr = 5 waves; wave w owns
// c = blockIdx.x*5 + w; lane = o.
// ============================================================================
__global__ void __launch_bounds__(320, 6)
caps_pass0(const float* __restrict__ x, const float* __restrict__ W,
           float* __restrict__ Sp, uint32_t* __restrict__ U)
{
    __shared__ float xs[RPC][BN][IN_];   // 16 KB
    const int chunk = blockIdx.y;
    const int r0 = chunk * RPC;

    for (int t = threadIdx.x; t < RPC * BN * 2; t += 320) {
        const int i4 = t & 1;
        const int rl = (t >> 1) & (RPC - 1);
        const int b  = t >> 7;
        const float4 val = *reinterpret_cast<const float4*>(
            x + (((size_t)b * RN + r0 + rl) * IN_) + i4 * 4);
        *reinterpret_cast<float4*>(&xs[rl][b][i4 * 4]) = val;
    }
    __syncthreads();

    const int wave = threadIdx.x >> 6;
    const int lane = threadIdx.x & 63;
    const int c = blockIdx.x * 5 + wave;

    float acc[BN];
    #pragma unroll
    for (int b = 0; b < BN; ++b) acc[b] = 0.f;

    #pragma unroll 2
    for (int rl = 0; rl < RPC; ++rl) {
        const int r = r0 + rl;
        const f4x* wp = reinterpret_cast<const f4x*>(
            W + ((((size_t)r * CN + c) * ON + lane) * IN_));
        const f4x w0 = __builtin_nontemporal_load(wp);
        const f4x w1 = __builtin_nontemporal_load(wp + 1);

        float u[BN];
        #pragma unroll
        for (int b = 0; b < BN; ++b) {
            const float4 xa = *reinterpret_cast<const float4*>(&xs[rl][b][0]);
            const float4 xb = *reinterpret_cast<const float4*>(&xs[rl][b][4]);
            u[b] = w0.x*xa.x + w0.y*xa.y + w0.z*xa.z + w0.w*xa.w
                 + w1.x*xb.x + w1.y*xb.y + w1.z*xb.z + w1.w*xb.w;
            acc[b] += u[b];
        }
        u4x q;
        q.x = pack_bf16(u[0], u[1]);
        q.y = pack_bf16(u[2], u[3]);
        q.z = pack_bf16(u[4], u[5]);
        q.w = pack_bf16(u[6], u[7]);
        __builtin_nontemporal_store(q, reinterpret_cast<u4x*>(
            U + (((size_t)r * CN + c) * ON + lane) * 4));
    }

    float* sp = Sp + (size_t)chunk * SOUT;
    #pragma unroll
    for (int b = 0; b < BN; ++b)
        sp[(b * CN + c) * ON + lane] = acc[b];
}

// ============================================================================
// passU<MODE> (R8 + unroll 3): read bf16 u_hat nt. MODE 1: b1 stored.
// MODE 2: b2 = b1(load) + mean_b<u,v1>. Sp/Zp partials per chunk.
// ============================================================================
template<int MODE>
__global__ void __launch_bounds__(320, 6)
caps_passU(const uint32_t* __restrict__ U, const float* __restrict__ vin,
           const float* __restrict__ bin, float* __restrict__ bout,
           float* __restrict__ Sp, float* __restrict__ Zp)
{
    const int chunk = blockIdx.y;
    const int r0 = chunk * RPC;
    const int wave = threadIdx.x >> 6;
    const int lane = threadIdx.x & 63;
    const int c = blockIdx.x * 5 + wave;

    float vreg[BN];
    #pragma unroll
    for (int b = 0; b < BN; ++b)
        vreg[b] = vin[(b * CN + c) * ON + lane];

    float acc[BN];
    #pragma unroll
    for (int b = 0; b < BN; ++b) acc[b] = 0.f;
    float zacc = 0.f;

    #pragma unroll 3
    for (int rl = 0; rl < RPC; ++rl) {
        const int r = r0 + rl;
        const u4x q = __builtin_nontemporal_load(reinterpret_cast<const u4x*>(
            U + (((size_t)r * CN + c) * ON + lane) * 4));
        float u[BN];
        u[0] = lo_bf16(q.x); u[1] = hi_bf16(q.x);
        u[2] = lo_bf16(q.y); u[3] = hi_bf16(q.y);
        u[4] = lo_bf16(q.z); u[5] = hi_bf16(q.z);
        u[6] = lo_bf16(q.w); u[7] = hi_bf16(q.w);

        float p = 0.f;
        #pragma unroll
        for (int b = 0; b < BN; ++b) p += u[b] * vreg[b];
        // sum over 64 lanes (= sum over o); butterfly, result in all lanes
        #pragma unroll
        for (int off = 32; off > 0; off >>= 1) p += __shfl_xor(p, off, 64);

        float bn = p * (1.0f / BN);
        if (MODE == 2) bn += bin[(size_t)r * CN + c];
        if (MODE == 1 && lane == 0) bout[(size_t)r * CN + c] = bn;
        const float e = __expf(bn);
        zacc += e;
        #pragma unroll
        for (int b = 0; b < BN; ++b) acc[b] += e * u[b];
    }

    float* sp = Sp + (size_t)chunk * SOUT;
    #pragma unroll
    for (int b = 0; b < BN; ++b)
        sp[(b * CN + c) * ON + lane] = acc[b];
    if (lane == 0)
        Zp[chunk * 32 + c] = zacc;
}

// ============================================================================
// fin<PASS> (widened): one block per (b,c); 1024 threads = 16 waves; wave g
// sums chunks g::16 (13 iters max); LDS tree; z inline (lane-parallel);
// squash; write.
// ============================================================================
template<int PASS>
__global__ void __launch_bounds__(1024)
caps_fin(const float* __restrict__ Sp, const float* __restrict__ Zp,
         float* __restrict__ vout)
{
    __shared__ float red[1024];
    const int wu = blockIdx.x;           // b*CN + c
    const int t = threadIdx.x, lane = t & 63, g = t >> 6;   // g in 0..15
    const int c = wu % CN;

    float z = (float)RN;
    if (PASS >= 1) {
        float zp = 0.f;
        for (int j = lane; j < NRC; j += 64) zp += Zp[j * 32 + c];
        #pragma unroll
        for (int off = 32; off > 0; off >>= 1) zp += __shfl_xor(zp, off, 64);
        z = zp;
    }
    const int base = wu * ON + lane;
    float s = 0.f;
    for (int ch = g; ch < NRC; ch += 16)
        s += Sp[(size_t)ch * SOUT + base];
    red[t] = s;
    __syncthreads();
    if (g == 0) {
        float ss = 0.f;
        #pragma unroll
        for (int k = 0; k < 16; ++k) ss += red[k * 64 + lane];
        ss /= z;
        vout[base] = squashf(ss);
    }
}

extern "C" void kernel_launch(void* const* d_in, const int* in_sizes, int n_in,
                              void* d_out, int out_size, void* d_ws, size_t ws_size,
                              hipStream_t stream)
{
    const float* x = (const float*)d_in[0];   // [B, R, I]
    const float* W = (const float*)d_in[1];   // [R, C, O, I]
    float* out = (float*)d_out;               // [B, C, O, 1] flat = 12800
    float* ws = (float*)d_ws;

    // Workspace (floats): v[SOUT] | b1[RN*CN] | Zp[NRC*32] | Sp[NRC*SOUT] | U
    float* v  = ws;
    float* b1 = v + SOUT;
    float* Zp = b1 + (size_t)RN * CN;
    float* Sp = Zp + (size_t)NRC * 32;
    uint32_t* U = (uint32_t*)(Sp + (size_t)NRC * SOUT);   // 327.7 MB bf16 u_hat, [r][c][o]

    dim3 blk(320), grid(5, NRC), fg(NFIN), fb(1024);

    // it 0: u = W·x (store bf16 nt), S0 partials; v0 = squash(S0/RN)
    caps_pass0<<<grid, blk, 0, stream>>>(x, W, Sp, U);
    caps_fin<0><<<fg, fb, 0, stream>>>(Sp, Zp, v);
    // it 1: b1 = mean_b<u,v0> (store); S1,Z1 partials; v1 = squash(S1/z1)
    caps_passU<1><<<grid, blk, 0, stream>>>(U, v, nullptr, b1, Sp, Zp);
    caps_fin<1><<<fg, fb, 0, stream>>>(Sp, Zp, v);
    // it 2: b2 = b1 + mean_b<u,v1>; S2,Z2 partials; out = squash(S2/z2)
    caps_passU<2><<<grid, blk, 0, stream>>>(U, v, b1, nullptr, Sp, Zp);
    caps_fin<2><<<fg, fb, 0, stream>>>(Sp, Zp, out);
}

// Round 11
// 366.649 us; speedup vs baseline: 2.1893x; 2.1893x over previous
//
#include <hip/hip_runtime.h>
#include <cstdint>
#include <cstddef>

// Problem constants
#define RN 12800   // routes
#define CN 25      // caps
#define ON 64      // out channels
#define IN_ 8      // in channels
#define BN 8       // batch
#define SOUT (BN*CN*ON)   // 12800 output elems

#define RPC 64            // routes per chunk
#define NRC (RN / RPC)    // 200 chunks
#define NFIN (BN * CN)    // 200 finalize blocks

typedef float    f4x __attribute__((ext_vector_type(4)));
typedef uint32_t u4x __attribute__((ext_vector_type(4)));

// ---- bf16 helpers (RNE) ----
__device__ __forceinline__ uint32_t pack_bf16(float a, float b) {
    uint32_t ua = __float_as_uint(a);
    uint32_t ub = __float_as_uint(b);
    ua = (ua + 0x7fffu + ((ua >> 16) & 1u)) >> 16;          // bf16(a) low half
    ub = (ub + 0x7fffu + ((ub >> 16) & 1u)) & 0xffff0000u;  // bf16(b) high half
    return ua | ub;
}
__device__ __forceinline__ float lo_bf16(uint32_t q) { return __uint_as_float(q << 16); }
__device__ __forceinline__ float hi_bf16(uint32_t q) { return __uint_as_float(q & 0xffff0000u); }
__device__ __forceinline__ float squashf(float s) { return s * fabsf(s) / (1.f + s * s); }

// ============================================================================
// pass0 (R8-identical): u = W·x; U stored bf16 nt [r][c][o]; W loads nt.
// Sp[chunk] partials regular. block = 320 thr = 5 waves; wave w owns
// c = blockIdx.x*5 + w; lane = o.
// ============================================================================
__global__ void __launch_bounds__(320, 6)
caps_pass0(const float* __restrict__ x, const float* __restrict__ W,
           float* __restrict__ Sp, uint32_t* __restrict__ U)
{
    __shared__ float xs[RPC][BN][IN_];   // 16 KB
    const int chunk = blockIdx.y;
    const int r0 = chunk * RPC;

    for (int t = threadIdx.x; t < RPC * BN * 2; t += 320) {
        const int i4 = t & 1;
        const int rl = (t >> 1) & (RPC - 1);
        const int b  = t >> 7;
        const float4 val = *reinterpret_cast<const float4*>(
            x + (((size_t)b * RN + r0 + rl) * IN_) + i4 * 4);
        *reinterpret_cast<float4*>(&xs[rl][b][i4 * 4]) = val;
    }
    __syncthreads();

    const int wave = threadIdx.x >> 6;
    const int lane = threadIdx.x & 63;
    const int c = blockIdx.x * 5 + wave;

    float acc[BN];
    #pragma unroll
    for (int b = 0; b < BN; ++b) acc[b] = 0.f;

    #pragma unroll 2
    for (int rl = 0; rl < RPC; ++rl) {
        const int r = r0 + rl;
        const f4x* wp = reinterpret_cast<const f4x*>(
            W + ((((size_t)r * CN + c) * ON + lane) * IN_));
        const f4x w0 = __builtin_nontemporal_load(wp);
        const f4x w1 = __builtin_nontemporal_load(wp + 1);

        float u[BN];
        #pragma unroll
        for (int b = 0; b < BN; ++b) {
            const float4 xa = *reinterpret_cast<const float4*>(&xs[rl][b][0]);
            const float4 xb = *reinterpret_cast<const float4*>(&xs[rl][b][4]);
            u[b] = w0.x*xa.x + w0.y*xa.y + w0.z*xa.z + w0.w*xa.w
                 + w1.x*xb.x + w1.y*xb.y + w1.z*xb.z + w1.w*xb.w;
            acc[b] += u[b];
        }
        u4x q;
        q.x = pack_bf16(u[0], u[1]);
        q.y = pack_bf16(u[2], u[3]);
        q.z = pack_bf16(u[4], u[5]);
        q.w = pack_bf16(u[6], u[7]);
        __builtin_nontemporal_store(q, reinterpret_cast<u4x*>(
            U + (((size_t)r * CN + c) * ON + lane) * 4));
    }

    float* sp = Sp + (size_t)chunk * SOUT;
    #pragma unroll
    for (int b = 0; b < BN; ++b)
        sp[(b * CN + c) * ON + lane] = acc[b];
}

// ============================================================================
// passU<MODE> (R8-identical, unroll 2 — unroll 3 spilled to scratch, R10):
// read bf16 u_hat nt. MODE 1: b1 stored. MODE 2: b2 = b1(load) +
// mean_b<u,v1>. Sp/Zp partials per chunk.
// ============================================================================
template<int MODE>
__global__ void __launch_bounds__(320, 6)
caps_passU(const uint32_t* __restrict__ U, const float* __restrict__ vin,
           const float* __restrict__ bin, float* __restrict__ bout,
           float* __restrict__ Sp, float* __restrict__ Zp)
{
    const int chunk = blockIdx.y;
    const int r0 = chunk * RPC;
    const int wave = threadIdx.x >> 6;
    const int lane = threadIdx.x & 63;
    const int c = blockIdx.x * 5 + wave;

    float vreg[BN];
    #pragma unroll
    for (int b = 0; b < BN; ++b)
        vreg[b] = vin[(b * CN + c) * ON + lane];

    float acc[BN];
    #pragma unroll
    for (int b = 0; b < BN; ++b) acc[b] = 0.f;
    float zacc = 0.f;

    #pragma unroll 2
    for (int rl = 0; rl < RPC; ++rl) {
        const int r = r0 + rl;
        const u4x q = __builtin_nontemporal_load(reinterpret_cast<const u4x*>(
            U + (((size_t)r * CN + c) * ON + lane) * 4));
        float u[BN];
        u[0] = lo_bf16(q.x); u[1] = hi_bf16(q.x);
        u[2] = lo_bf16(q.y); u[3] = hi_bf16(q.y);
        u[4] = lo_bf16(q.z); u[5] = hi_bf16(q.z);
        u[6] = lo_bf16(q.w); u[7] = hi_bf16(q.w);

        float p = 0.f;
        #pragma unroll
        for (int b = 0; b < BN; ++b) p += u[b] * vreg[b];
        // sum over 64 lanes (= sum over o); butterfly, result in all lanes
        #pragma unroll
        for (int off = 32; off > 0; off >>= 1) p += __shfl_xor(p, off, 64);

        float bn = p * (1.0f / BN);
        if (MODE == 2) bn += bin[(size_t)r * CN + c];
        if (MODE == 1 && lane == 0) bout[(size_t)r * CN + c] = bn;
        const float e = __expf(bn);
        zacc += e;
        #pragma unroll
        for (int b = 0; b < BN; ++b) acc[b] += e * u[b];
    }

    float* sp = Sp + (size_t)chunk * SOUT;
    #pragma unroll
    for (int b = 0; b < BN; ++b)
        sp[(b * CN + c) * ON + lane] = acc[b];
    if (lane == 0)
        Zp[chunk * 32 + c] = zacc;
}

// ============================================================================
// fin<PASS> (widened, kept from R9): one block per (b,c); 1024 threads =
// 16 waves; wave g sums chunks g::16 (~13 iters); LDS tree; z inline
// (lane-parallel); squash; write.
// ============================================================================
template<int PASS>
__global__ void __launch_bounds__(1024)
caps_fin(const float* __restrict__ Sp, const float* __restrict__ Zp,
         float* __restrict__ vout)
{
    __shared__ float red[1024];
    const int wu = blockIdx.x;           // b*CN + c
    const int t = threadIdx.x, lane = t & 63, g = t >> 6;   // g in 0..15
    const int c = wu % CN;

    float z = (float)RN;
    if (PASS >= 1) {
        float zp = 0.f;
        for (int j = lane; j < NRC; j += 64) zp += Zp[j * 32 + c];
        #pragma unroll
        for (int off = 32; off > 0; off >>= 1) zp += __shfl_xor(zp, off, 64);
        z = zp;
    }
    const int base = wu * ON + lane;
    float s = 0.f;
    for (int ch = g; ch < NRC; ch += 16)
        s += Sp[(size_t)ch * SOUT + base];
    red[t] = s;
    __syncthreads();
    if (g == 0) {
        float ss = 0.f;
        #pragma unroll
        for (int k = 0; k < 16; ++k) ss += red[k * 64 + lane];
        ss /= z;
        vout[base] = squashf(ss);
    }
}

extern "C" void kernel_launch(void* const* d_in, const int* in_sizes, int n_in,
                              void* d_out, int out_size, void* d_ws, size_t ws_size,
                              hipStream_t stream)
{
    const float* x = (const float*)d_in[0];   // [B, R, I]
    const float* W = (const float*)d_in[1];   // [R, C, O, I]
    float* out = (float*)d_out;               // [B, C, O, 1] flat = 12800
    float* ws = (float*)d_ws;

    // Workspace (floats): v[SOUT] | b1[RN*CN] | Zp[NRC*32] | Sp[NRC*SOUT] | U
    float* v  = ws;
    float* b1 = v + SOUT;
    float* Zp = b1 + (size_t)RN * CN;
    float* Sp = Zp + (size_t)NRC * 32;
    uint32_t* U = (uint32_t*)(Sp + (size_t)NRC * SOUT);   // 327.7 MB bf16 u_hat, [r][c][o]

    dim3 blk(320), grid(5, NRC), fg(NFIN), fb(1024);

    // it 0: u = W·x (store bf16 nt), S0 partials; v0 = squash(S0/RN)
    caps_pass0<<<grid, blk, 0, stream>>>(x, W, Sp, U);
    caps_fin<0><<<fg, fb, 0, stream>>>(Sp, Zp, v);
    // it 1: b1 = mean_b<u,v0> (store); S1,Z1 partials; v1 = squash(S1/z1)
    caps_passU<1><<<grid, blk, 0, stream>>>(U, v, nullptr, b1, Sp, Zp);
    caps_fin<1><<<fg, fb, 0, stream>>>(Sp, Zp, v);
    // it 2: b2 = b1 + mean_b<u,v1>; S2,Z2 partials; out = squash(S2/z2)
    caps_passU<2><<<grid, blk, 0, stream>>>(U, v, b1, nullptr, Sp, Zp);
    caps_fin<2><<<fg, fb, 0, stream>>>(Sp, Zp, out);
}

// Round 13
// 354.870 us; speedup vs baseline: 2.2620x; 1.0332x over previous
//
#include <hip/hip_runtime.h>
#include <cstdint>
#include <cstddef>

// Problem constants
#define RN 12800   // routes
#define CN 25      // caps
#define ON 64      // out channels
#define IN_ 8      // in channels
#define BN 8       // batch
#define SOUT (BN*CN*ON)   // 12800 output elems

#define RPC 64            // routes per chunk
#define NRC (RN / RPC)    // 200 chunks
#define NFIN (BN * CN)    // 200 finalize blocks

typedef float    f4x __attribute__((ext_vector_type(4)));
typedef uint32_t u4x __attribute__((ext_vector_type(4)));

// ---- bf16 helpers ----
__device__ __forceinline__ uint32_t pack_bf16_hw(float a, float b) {
    // RNE pack via hardware v_cvt_pk_bf16_f32 (no builtin on gfx950 — inline asm,
    // per guide T12/m240). a -> low 16, b -> high 16.
    uint32_t q;
    asm("v_cvt_pk_bf16_f32 %0, %1, %2" : "=v"(q) : "v"(a), "v"(b));
    return q;
}
__device__ __forceinline__ float lo_bf16(uint32_t q) { return __uint_as_float(q << 16); }
__device__ __forceinline__ float hi_bf16(uint32_t q) { return __uint_as_float(q & 0xffff0000u); }
__device__ __forceinline__ float squashf(float s) { return s * fabsf(s) / (1.f + s * s); }

// ============================================================================
// pass0 (VALU diet vs R8): u = W·x; U stored bf16 nt [r][c][o]; W loads nt.
// x read via WAVE-UNIFORM loads (scalar pipe, no LDS staging, no barriers);
// bf16 pack via v_cvt_pk_bf16_f32. Sp[chunk] partials regular.
// block = 320 thr = 5 waves; wave w owns c = blockIdx.x*5 + w; lane = o.
// ============================================================================
__global__ void __launch_bounds__(320, 6)
caps_pass0(const float* __restrict__ x, const float* __restrict__ W,
           float* __restrict__ Sp, uint32_t* __restrict__ U)
{
    const int chunk = blockIdx.y;
    const int r0 = chunk * RPC;
    const int wave = threadIdx.x >> 6;
    const int lane = threadIdx.x & 63;
    const int c = blockIdx.x * 5 + wave;

    float acc[BN];
    #pragma unroll
    for (int b = 0; b < BN; ++b) acc[b] = 0.f;

    #pragma unroll 2
    for (int rl = 0; rl < RPC; ++rl) {
        const int r = r0 + rl;
        const f4x* wp = reinterpret_cast<const f4x*>(
            W + ((((size_t)r * CN + c) * ON + lane) * IN_));
        const f4x w0 = __builtin_nontemporal_load(wp);
        const f4x w1 = __builtin_nontemporal_load(wp + 1);

        float u[BN];
        #pragma unroll
        for (int b = 0; b < BN; ++b) {
            // wave-uniform address (b, r only) -> scalar loads, broadcast to lanes
            const float4 xa = *reinterpret_cast<const float4*>(
                x + (((size_t)b * RN + r) * IN_));
            const float4 xb = *reinterpret_cast<const float4*>(
                x + (((size_t)b * RN + r) * IN_) + 4);
            u[b] = w0.x*xa.x + w0.y*xa.y + w0.z*xa.z + w0.w*xa.w
                 + w1.x*xb.x + w1.y*xb.y + w1.z*xb.z + w1.w*xb.w;
            acc[b] += u[b];
        }
        u4x q;
        q.x = pack_bf16_hw(u[0], u[1]);
        q.y = pack_bf16_hw(u[2], u[3]);
        q.z = pack_bf16_hw(u[4], u[5]);
        q.w = pack_bf16_hw(u[6], u[7]);
        __builtin_nontemporal_store(q, reinterpret_cast<u4x*>(
            U + (((size_t)r * CN + c) * ON + lane) * 4));
    }

    float* sp = Sp + (size_t)chunk * SOUT;
    #pragma unroll
    for (int b = 0; b < BN; ++b)
        sp[(b * CN + c) * ON + lane] = acc[b];
}

// ============================================================================
// passU<MODE> (R8-identical): read bf16 u_hat nt. MODE 1: b1 stored.
// MODE 2: b2 = b1(load) + mean_b<u,v1>. Sp/Zp partials per chunk.
// ============================================================================
template<int MODE>
__global__ void __launch_bounds__(320, 6)
caps_passU(const uint32_t* __restrict__ U, const float* __restrict__ vin,
           const float* __restrict__ bin, float* __restrict__ bout,
           float* __restrict__ Sp, float* __restrict__ Zp)
{
    const int chunk = blockIdx.y;
    const int r0 = chunk * RPC;
    const int wave = threadIdx.x >> 6;
    const int lane = threadIdx.x & 63;
    const int c = blockIdx.x * 5 + wave;

    float vreg[BN];
    #pragma unroll
    for (int b = 0; b < BN; ++b)
        vreg[b] = vin[(b * CN + c) * ON + lane];

    float acc[BN];
    #pragma unroll
    for (int b = 0; b < BN; ++b) acc[b] = 0.f;
    float zacc = 0.f;

    #pragma unroll 2
    for (int rl = 0; rl < RPC; ++rl) {
        const int r = r0 + rl;
        const u4x q = __builtin_nontemporal_load(reinterpret_cast<const u4x*>(
            U + (((size_t)r * CN + c) * ON + lane) * 4));
        float u[BN];
        u[0] = lo_bf16(q.x); u[1] = hi_bf16(q.x);
        u[2] = lo_bf16(q.y); u[3] = hi_bf16(q.y);
        u[4] = lo_bf16(q.z); u[5] = hi_bf16(q.z);
        u[6] = lo_bf16(q.w); u[7] = hi_bf16(q.w);

        float p = 0.f;
        #pragma unroll
        for (int b = 0; b < BN; ++b) p += u[b] * vreg[b];
        // sum over 64 lanes (= sum over o); butterfly, result in all lanes
        #pragma unroll
        for (int off = 32; off > 0; off >>= 1) p += __shfl_xor(p, off, 64);

        float bn = p * (1.0f / BN);
        if (MODE == 2) bn += bin[(size_t)r * CN + c];
        if (MODE == 1 && lane == 0) bout[(size_t)r * CN + c] = bn;
        const float e = __expf(bn);
        zacc += e;
        #pragma unroll
        for (int b = 0; b < BN; ++b) acc[b] += e * u[b];
    }

    float* sp = Sp + (size_t)chunk * SOUT;
    #pragma unroll
    for (int b = 0; b < BN; ++b)
        sp[(b * CN + c) * ON + lane] = acc[b];
    if (lane == 0)
        Zp[chunk * 32 + c] = zacc;
}

// ============================================================================
// fin<PASS> (R8-identical): one block per (b,c); z inline from Zp
// (lane-parallel) or RN; 5 groups of 64 lanes each sum 40 chunks of Sp;
// LDS reduce; squash; write.
// ============================================================================
template<int PASS>
__global__ void __launch_bounds__(320)
caps_fin(const float* __restrict__ Sp, const float* __restrict__ Zp,
         float* __restrict__ vout)
{
    __shared__ float red[320];
    const int wu = blockIdx.x;           // b*CN + c
    const int t = threadIdx.x, lane = t & 63, g = t >> 6;
    const int c = wu % CN;

    float z = (float)RN;
    if (PASS >= 1) {
        float zp = 0.f;
        for (int j = lane; j < NRC; j += 64) zp += Zp[j * 32 + c];
        #pragma unroll
        for (int off = 32; off > 0; off >>= 1) zp += __shfl_xor(zp, off, 64);
        z = zp;
    }
    const int base = wu * ON + lane;
    float s = 0.f;
    for (int ch = g * 40; ch < g * 40 + 40; ++ch)
        s += Sp[(size_t)ch * SOUT + base];
    red[t] = s;
    __syncthreads();
    if (g == 0) {
        float ss = red[lane] + red[64 + lane] + red[128 + lane]
                 + red[192 + lane] + red[256 + lane];
        ss /= z;
        vout[base] = squashf(ss);
    }
}

extern "C" void kernel_launch(void* const* d_in, const int* in_sizes, int n_in,
                              void* d_out, int out_size, void* d_ws, size_t ws_size,
                              hipStream_t stream)
{
    const float* x = (const float*)d_in[0];   // [B, R, I]
    const float* W = (const float*)d_in[1];   // [R, C, O, I]
    float* out = (float*)d_out;               // [B, C, O, 1] flat = 12800
    float* ws = (float*)d_ws;

    // Workspace (floats): v[SOUT] | b1[RN*CN] | Zp[NRC*32] | Sp[NRC*SOUT] | U
    float* v  = ws;
    float* b1 = v + SOUT;
    float* Zp = b1 + (size_t)RN * CN;
    float* Sp = Zp + (size_t)NRC * 32;
    uint32_t* U = (uint32_t*)(Sp + (size_t)NRC * SOUT);   // 327.7 MB bf16 u_hat, [r][c][o]

    dim3 blk(320), grid(5, NRC), fg(NFIN);

    // it 0: u = W·x (store bf16 nt), S0 partials; v0 = squash(S0/RN)
    caps_pass0<<<grid, blk, 0, stream>>>(x, W, Sp, U);
    caps_fin<0><<<fg, blk, 0, stream>>>(Sp, Zp, v);
    // it 1: b1 = mean_b<u,v0> (store); S1,Z1 partials; v1 = squash(S1/z1)
    caps_passU<1><<<grid, blk, 0, stream>>>(U, v, nullptr, b1, Sp, Zp);
    caps_fin<1><<<fg, blk, 0, stream>>>(Sp, Zp, v);
    // it 2: b2 = b1 + mean_b<u,v1>; S2,Z2 partials; out = squash(S2/z2)
    caps_passU<2><<<grid, blk, 0, stream>>>(U, v, b1, nullptr, Sp, Zp);
    caps_fin<2><<<fg, blk, 0, stream>>>(Sp, Zp, out);
}